// Round 1
// baseline (179.909 us; speedup 1.0000x reference)
//
#include <hip/hip_runtime.h>
#include <cstddef>

#define B_     4096
#define L_     64
#define OUT_   64
#define KS_    8
#define KK_    4
#define LOUT_  57
#define C_     3648      // OUT_*LOUT_
#define HID_   33
#define TEMP_  34.0f
#define EPS_   1e-5f
#define NCHUNK 16
#define NB2    8

__device__ __forceinline__ float gelu_f(float x) {
    // tanh-form gelu: x * sigmoid(1.5957691*x*(1+0.044715x^2)); max abs err ~5e-4
    float u = x * fmaf(0.044715f * x, x, 1.0f) * -1.5957691216f;
    return x / (1.0f + __expf(u));
}

// ---------------- kernel 1: attention weights ----------------
__global__ __launch_bounds__(256) void attn_kernel(
    const float* __restrict__ x, const float* __restrict__ fc1_w,
    const float* __restrict__ fc2_w, const float* __restrict__ fc2_b,
    float* __restrict__ attn_out)
{
    __shared__ float fc1s[HID_][L_];
    __shared__ float fc2s[KK_][HID_];
    __shared__ float fc2bs[KK_];
    int tid = threadIdx.x;
    for (int i = tid; i < HID_ * L_; i += 256) fc1s[i / L_][i % L_] = fc1_w[i];
    for (int i = tid; i < KK_ * HID_; i += 256) fc2s[i / HID_][i % HID_] = fc2_w[i];
    if (tid < KK_) fc2bs[tid] = fc2_b[tid];
    __syncthreads();

    int b = blockIdx.x * 256 + tid;
    if (b >= B_) return;

    float xr[L_];
    const float4* xp = (const float4*)(x + (size_t)b * L_);
    #pragma unroll
    for (int i = 0; i < L_ / 4; ++i) {
        float4 v = xp[i];
        xr[4*i] = v.x; xr[4*i+1] = v.y; xr[4*i+2] = v.z; xr[4*i+3] = v.w;
    }
    float logit[KK_] = {0.f, 0.f, 0.f, 0.f};
    for (int h = 0; h < HID_; ++h) {
        const float4* fr = (const float4*)&fc1s[h][0];
        float acc = 0.f;
        #pragma unroll
        for (int i = 0; i < L_ / 4; ++i) {
            float4 wv = fr[i];
            acc = fmaf(xr[4*i],   wv.x, acc);
            acc = fmaf(xr[4*i+1], wv.y, acc);
            acc = fmaf(xr[4*i+2], wv.z, acc);
            acc = fmaf(xr[4*i+3], wv.w, acc);
        }
        float a = gelu_f(acc);
        #pragma unroll
        for (int k = 0; k < KK_; ++k) logit[k] = fmaf(a, fc2s[k][h], logit[k]);
    }
    float z[KK_];
    #pragma unroll
    for (int k = 0; k < KK_; ++k) z[k] = (logit[k] + fc2bs[k]) * (1.0f / TEMP_);
    float mx = fmaxf(fmaxf(z[0], z[1]), fmaxf(z[2], z[3]));
    float e[KK_]; float s = 0.f;
    #pragma unroll
    for (int k = 0; k < KK_; ++k) { e[k] = __expf(z[k] - mx); s += e[k]; }
    float inv = 1.0f / s;
    #pragma unroll
    for (int k = 0; k < KK_; ++k) attn_out[(size_t)b * KK_ + k] = e[k] * inv;
}

// ---------------- kernel 2: batch statistics ----------------
__global__ __launch_bounds__(256) void stats_kernel(
    const float* __restrict__ x, const float* __restrict__ weight,
    const float* __restrict__ bias, const float* __restrict__ attn,
    float* __restrict__ S)
{
    int o = blockIdx.x;       // 0..63
    int chunk = blockIdx.y;   // 0..NCHUNK-1
    int tid = threadIdx.x;
    int r = tid >> 6;         // 0..3
    int l = tid & 63;         // 0..63
    bool act = l < LOUT_;

    float w[KK_][KS_];
    float bk[KK_];
    #pragma unroll
    for (int k = 0; k < KK_; ++k) {
        bk[k] = bias[k * OUT_ + o];
        #pragma unroll
        for (int c = 0; c < KS_; ++c) w[k][c] = weight[(k * OUT_ + o) * KS_ + c];
    }

    __shared__ float xs[4][L_];
    __shared__ float at[4][KK_];
    __shared__ float red[4][L_][4];

    float s1 = 0.f, s2 = 0.f, t1 = 0.f, t2 = 0.f;
    const int CH = B_ / NCHUNK;   // 256
    int b0base = chunk * CH;

    for (int it = 0; it < CH / 4; ++it) {
        int b0 = b0base + it * 4;
        __syncthreads();
        xs[r][l] = x[(size_t)(b0 + r) * L_ + l];
        if (tid < 16) at[tid >> 2][tid & 3] = attn[(size_t)(b0 + (tid >> 2)) * KK_ + (tid & 3)];
        __syncthreads();
        if (act) {
            float kv0 = bk[0], kv1 = bk[1], kv2 = bk[2], kv3 = bk[3];
            #pragma unroll
            for (int c = 0; c < KS_; ++c) {
                float xv = xs[r][l + c];
                kv0 = fmaf(xv, w[0][c], kv0);
                kv1 = fmaf(xv, w[1][c], kv1);
                kv2 = fmaf(xv, w[2][c], kv2);
                kv3 = fmaf(xv, w[3][c], kv3);
            }
            float ov = at[r][0] * kv0;
            ov = fmaf(at[r][1], kv1, ov);
            ov = fmaf(at[r][2], kv2, ov);
            ov = fmaf(at[r][3], kv3, ov);
            float g = gelu_f(ov);
            s1 += g; s2 = fmaf(g, g, s2);
            float g20 = gelu_f(kv0), g21 = gelu_f(kv1), g22 = gelu_f(kv2), g23 = gelu_f(kv3);
            t1 += g20 + g21 + g22 + g23;
            t2 = fmaf(g20, g20, t2); t2 = fmaf(g21, g21, t2);
            t2 = fmaf(g22, g22, t2); t2 = fmaf(g23, g23, t2);
        }
    }
    __syncthreads();
    red[r][l][0] = s1; red[r][l][1] = s2; red[r][l][2] = t1; red[r][l][3] = t2;
    __syncthreads();
    if (r == 0 && act) {
        float a0 = 0.f, a1 = 0.f, a2 = 0.f, a3 = 0.f;
        #pragma unroll
        for (int q = 0; q < 4; ++q) {
            a0 += red[q][l][0]; a1 += red[q][l][1];
            a2 += red[q][l][2]; a3 += red[q][l][3];
        }
        int c = o * LOUT_ + l;
        atomicAdd(&S[c], a0);
        atomicAdd(&S[C_ + c], a1);
        atomicAdd(&S[2 * C_ + c], a2);
        atomicAdd(&S[3 * C_ + c], a3);
    }
}

// ---------------- kernel 3: fold stats into scale/shift ----------------
__global__ __launch_bounds__(256) void finalize_kernel(
    const float* __restrict__ S, const float* __restrict__ gamma,
    const float* __restrict__ beta, float* __restrict__ F)
{
    int c = blockIdx.x * 256 + threadIdx.x;
    if (c >= C_) return;
    float m  = S[c] * (1.0f / B_);
    float v  = S[C_ + c] * (1.0f / B_) - m * m;
    float rs = rsqrtf(v + EPS_);
    float m2 = S[2 * C_ + c] * (1.0f / (B_ * KK_));
    float v2 = S[3 * C_ + c] * (1.0f / (B_ * KK_)) - m2 * m2;
    float rs2 = rsqrtf(v2 + EPS_);
    float ga = gamma[c], be = beta[c];
    F[c]          = rs * ga;             // scaleA
    F[C_ + c]     = be - m * rs * ga;    // shiftA
    F[2 * C_ + c] = rs2 * ga;            // scaleK
    F[3 * C_ + c] = be - m2 * rs2 * ga;  // shiftK
}

// ---------------- kernel 4: recompute + normalize + write ----------------
__global__ __launch_bounds__(256) void write_kernel(
    const float* __restrict__ x, const float* __restrict__ weight,
    const float* __restrict__ bias, const float* __restrict__ attn,
    const float* __restrict__ F,
    float* __restrict__ out0, float* __restrict__ kwout)
{
    int cc = blockIdx.x;    // 0..14
    int bg = blockIdx.y;    // 0..B/NB2-1
    int tid = threadIdx.x;
    int c = cc * 256 + tid;
    bool act = c < C_;
    int o = act ? (c / LOUT_) : 0;
    int l = act ? (c - o * LOUT_) : 0;

    float w[KK_][KS_];
    float bk[KK_];
    #pragma unroll
    for (int k = 0; k < KK_; ++k) {
        bk[k] = bias[k * OUT_ + o];
        #pragma unroll
        for (int cq = 0; cq < KS_; ++cq) w[k][cq] = weight[(k * OUT_ + o) * KS_ + cq];
    }
    float sA = 0.f, hA = 0.f, sK = 0.f, hK = 0.f;
    if (act) {
        sA = F[c]; hA = F[C_ + c]; sK = F[2 * C_ + c]; hK = F[3 * C_ + c];
    }

    __shared__ float xs[NB2][L_];
    __shared__ float at[NB2][KK_];
    int b0 = bg * NB2;
    for (int i = tid; i < NB2 * L_; i += 256)
        xs[i >> 6][i & 63] = x[(size_t)(b0 + (i >> 6)) * L_ + (i & 63)];
    if (tid < NB2 * KK_)
        at[tid >> 2][tid & 3] = attn[(size_t)(b0 + (tid >> 2)) * KK_ + (tid & 3)];
    __syncthreads();

    if (!act) return;

    #pragma unroll
    for (int r = 0; r < NB2; ++r) {
        float kv0 = bk[0], kv1 = bk[1], kv2 = bk[2], kv3 = bk[3];
        #pragma unroll
        for (int cq = 0; cq < KS_; ++cq) {
            float xv = xs[r][l + cq];
            kv0 = fmaf(xv, w[0][cq], kv0);
            kv1 = fmaf(xv, w[1][cq], kv1);
            kv2 = fmaf(xv, w[2][cq], kv2);
            kv3 = fmaf(xv, w[3][cq], kv3);
        }
        float ov = at[r][0] * kv0;
        ov = fmaf(at[r][1], kv1, ov);
        ov = fmaf(at[r][2], kv2, ov);
        ov = fmaf(at[r][3], kv3, ov);
        int b = b0 + r;
        float g = gelu_f(ov);
        out0[(size_t)b * C_ + c] = fmaf(g, sA, hA);
        float g0 = gelu_f(kv0), g1 = gelu_f(kv1), g2v = gelu_f(kv2), g3 = gelu_f(kv3);
        size_t base = (size_t)b * KK_ * C_ + c;
        kwout[base]           = fmaf(g0,  sK, hK);
        kwout[base + C_]      = fmaf(g1,  sK, hK);
        kwout[base + 2 * C_]  = fmaf(g2v, sK, hK);
        kwout[base + 3 * C_]  = fmaf(g3,  sK, hK);
    }
}

extern "C" void kernel_launch(void* const* d_in, const int* in_sizes, int n_in,
                              void* d_out, int out_size, void* d_ws, size_t ws_size,
                              hipStream_t stream) {
    const float* x      = (const float*)d_in[0];
    const float* fc1_w  = (const float*)d_in[1];
    const float* fc2_w  = (const float*)d_in[2];
    const float* fc2_b  = (const float*)d_in[3];
    const float* weight = (const float*)d_in[4];
    const float* bias   = (const float*)d_in[5];
    const float* gamma  = (const float*)d_in[6];
    const float* beta   = (const float*)d_in[7];

    float* out  = (float*)d_out;
    float* out0 = out;                          // B*C
    float* attn = out + (size_t)B_ * C_;        // B*K
    float* kwout = attn + (size_t)B_ * KK_;     // B*K*C

    float* S = (float*)d_ws;        // 4*C stats sums
    float* F = S + 4 * C_;          // 4*C scale/shift

    hipMemsetAsync(S, 0, 4 * C_ * sizeof(float), stream);
    attn_kernel<<<B_ / 256, 256, 0, stream>>>(x, fc1_w, fc2_w, fc2_b, attn);
    stats_kernel<<<dim3(OUT_, NCHUNK), 256, 0, stream>>>(x, weight, bias, attn, S);
    finalize_kernel<<<(C_ + 255) / 256, 256, 0, stream>>>(S, gamma, beta, F);
    write_kernel<<<dim3((C_ + 255) / 256, B_ / NB2), 256, 0, stream>>>(
        x, weight, bias, attn, F, out0, kwout);
}

// Round 2
// 167.469 us; speedup vs baseline: 1.0743x; 1.0743x over previous
//
#include <hip/hip_runtime.h>
#include <cstddef>

#define B_     4096
#define L_     64
#define OUT_   64
#define KS_    8
#define KK_    4
#define LOUT_  57
#define C_     3648      // OUT_*LOUT_
#define HID_   33
#define TEMP_  34.0f
#define EPS_   1e-5f
#define NCH_   32        // b-chunks for stats (128 rows each)
#define SROWS_ 32        // rows staged per barrier round in stats
#define NB2_   16        // rows per block in write kernel

__device__ __forceinline__ float gelu_f(float x) {
    // tanh-form gelu: x * sigmoid(1.5957691*x*(1+0.044715x^2)); max abs err ~5e-4
    float u = x * fmaf(0.044715f * x, x, 1.0f) * -1.5957691216f;
    return x / (1.0f + __expf(u));
}

// ---------------- kernel 1: attention weights ----------------
__global__ __launch_bounds__(128) void attn_kernel(
    const float* __restrict__ x, const float* __restrict__ fc1_w,
    const float* __restrict__ fc2_w, const float* __restrict__ fc2_b,
    float* __restrict__ attn_out)
{
    __shared__ float fc1s[HID_][L_];
    __shared__ float fc2s[KK_][HID_];
    __shared__ float fc2bs[KK_];
    int tid = threadIdx.x;
    for (int i = tid; i < HID_ * L_; i += 128) fc1s[i / L_][i % L_] = fc1_w[i];
    for (int i = tid; i < KK_ * HID_; i += 128) fc2s[i / HID_][i % HID_] = fc2_w[i];
    if (tid < KK_) fc2bs[tid] = fc2_b[tid];
    __syncthreads();

    int b = blockIdx.x * 128 + tid;
    if (b >= B_) return;

    float xr[L_];
    const float4* xp = (const float4*)(x + (size_t)b * L_);
    #pragma unroll
    for (int i = 0; i < L_ / 4; ++i) {
        float4 v = xp[i];
        xr[4*i] = v.x; xr[4*i+1] = v.y; xr[4*i+2] = v.z; xr[4*i+3] = v.w;
    }
    float logit[KK_] = {0.f, 0.f, 0.f, 0.f};
    for (int h = 0; h < HID_; ++h) {
        const float4* fr = (const float4*)&fc1s[h][0];
        float acc = 0.f;
        #pragma unroll
        for (int i = 0; i < L_ / 4; ++i) {
            float4 wv = fr[i];
            acc = fmaf(xr[4*i],   wv.x, acc);
            acc = fmaf(xr[4*i+1], wv.y, acc);
            acc = fmaf(xr[4*i+2], wv.z, acc);
            acc = fmaf(xr[4*i+3], wv.w, acc);
        }
        float a = gelu_f(acc);
        #pragma unroll
        for (int k = 0; k < KK_; ++k) logit[k] = fmaf(a, fc2s[k][h], logit[k]);
    }
    float z[KK_];
    #pragma unroll
    for (int k = 0; k < KK_; ++k) z[k] = (logit[k] + fc2bs[k]) * (1.0f / TEMP_);
    float mx = fmaxf(fmaxf(z[0], z[1]), fmaxf(z[2], z[3]));
    float e[KK_]; float s = 0.f;
    #pragma unroll
    for (int k = 0; k < KK_; ++k) { e[k] = __expf(z[k] - mx); s += e[k]; }
    float inv = 1.0f / s;
    #pragma unroll
    for (int k = 0; k < KK_; ++k) attn_out[(size_t)b * KK_ + k] = e[k] * inv;
}

// ---------------- kernel 2: batch statistics ----------------
// grid (15 c-tiles, NCH_ b-chunks); 128 rows/chunk staged SROWS_ at a time.
// Partial sums: P[(chunk*4 + stat)*C_ + c]  (no atomics).  Fallback: atomics to S.
__global__ __launch_bounds__(256) void stats_kernel(
    const float* __restrict__ x, const float* __restrict__ weight,
    const float* __restrict__ bias, const float* __restrict__ attn,
    float* __restrict__ P, int use_partial)
{
    const int RPC = B_ / NCH_;          // 128 rows per chunk
    int cb = blockIdx.x;
    int chunk = blockIdx.y;
    int tid = threadIdx.x;
    int c = cb * 256 + tid;
    bool act = c < C_;
    int o = act ? (c / LOUT_) : 0;
    int l = act ? (c - o * LOUT_) : 0;

    float w[KK_][KS_];
    float bk[KK_];
    #pragma unroll
    for (int k = 0; k < KK_; ++k) {
        bk[k] = bias[k * OUT_ + o];
        #pragma unroll
        for (int cq = 0; cq < KS_; ++cq) w[k][cq] = weight[(k * OUT_ + o) * KS_ + cq];
    }

    __shared__ float xs[SROWS_][L_];
    __shared__ float at[SROWS_][KK_];

    float s1 = 0.f, s2 = 0.f, t1 = 0.f, t2 = 0.f;

    for (int round = 0; round < RPC / SROWS_; ++round) {
        int b0 = chunk * RPC + round * SROWS_;
        __syncthreads();
        {   // stage SROWS_ rows of x: 512 float4, 2 per thread, coalesced
            const float4* xp4 = (const float4*)(x + (size_t)b0 * L_);
            float4* xd = (float4*)&xs[0][0];
            xd[tid] = xp4[tid];
            xd[tid + 256] = xp4[tid + 256];
            if (tid < SROWS_ * KK_) ((float*)at)[tid] = attn[(size_t)b0 * KK_ + tid];
        }
        __syncthreads();
        if (act) {
            #pragma unroll 4
            for (int r = 0; r < SROWS_; ++r) {
                float kv0 = bk[0], kv1 = bk[1], kv2 = bk[2], kv3 = bk[3];
                #pragma unroll
                for (int cq = 0; cq < KS_; ++cq) {
                    float xv = xs[r][l + cq];
                    kv0 = fmaf(xv, w[0][cq], kv0);
                    kv1 = fmaf(xv, w[1][cq], kv1);
                    kv2 = fmaf(xv, w[2][cq], kv2);
                    kv3 = fmaf(xv, w[3][cq], kv3);
                }
                float ov = at[r][0] * kv0;
                ov = fmaf(at[r][1], kv1, ov);
                ov = fmaf(at[r][2], kv2, ov);
                ov = fmaf(at[r][3], kv3, ov);
                float g = gelu_f(ov);
                s1 += g; s2 = fmaf(g, g, s2);
                float g0 = gelu_f(kv0), g1 = gelu_f(kv1), g2 = gelu_f(kv2), g3 = gelu_f(kv3);
                t1 += g0 + g1 + g2 + g3;
                t2 = fmaf(g0, g0, t2); t2 = fmaf(g1, g1, t2);
                t2 = fmaf(g2, g2, t2); t2 = fmaf(g3, g3, t2);
            }
        }
    }
    if (!act) return;
    if (use_partial) {
        size_t base = (size_t)chunk * 4 * C_ + c;
        P[base]          = s1;
        P[base + C_]     = s2;
        P[base + 2 * C_] = t1;
        P[base + 3 * C_] = t2;
    } else {
        atomicAdd(&P[c], s1);
        atomicAdd(&P[C_ + c], s2);
        atomicAdd(&P[2 * C_ + c], t1);
        atomicAdd(&P[3 * C_ + c], t2);
    }
}

// ---------------- kernel 3: reduce partials, fold into scale/shift ----------------
__global__ __launch_bounds__(256) void finalize_kernel(
    const float* __restrict__ P, const float* __restrict__ gamma,
    const float* __restrict__ beta, float* __restrict__ F, int use_partial)
{
    int c = blockIdx.x * 256 + threadIdx.x;
    if (c >= C_) return;
    float a0, a1, a2, a3;
    if (use_partial) {
        a0 = a1 = a2 = a3 = 0.f;
        for (int ch = 0; ch < NCH_; ++ch) {
            size_t base = (size_t)ch * 4 * C_ + c;
            a0 += P[base];
            a1 += P[base + C_];
            a2 += P[base + 2 * C_];
            a3 += P[base + 3 * C_];
        }
    } else {
        a0 = P[c]; a1 = P[C_ + c]; a2 = P[2 * C_ + c]; a3 = P[3 * C_ + c];
    }
    float m  = a0 * (1.0f / B_);
    float v  = a1 * (1.0f / B_) - m * m;
    float rs = rsqrtf(v + EPS_);
    float m2 = a2 * (1.0f / (B_ * KK_));
    float v2 = a3 * (1.0f / (B_ * KK_)) - m2 * m2;
    float rs2 = rsqrtf(v2 + EPS_);
    float ga = gamma[c], be = beta[c];
    F[c]          = rs * ga;             // scaleA
    F[C_ + c]     = be - m * rs * ga;    // shiftA
    F[2 * C_ + c] = rs2 * ga;            // scaleK
    F[3 * C_ + c] = be - m2 * rs2 * ga;  // shiftK
}

// ---------------- kernel 4: recompute + normalize + write ----------------
__global__ __launch_bounds__(256) void write_kernel(
    const float* __restrict__ x, const float* __restrict__ weight,
    const float* __restrict__ bias, const float* __restrict__ attn,
    const float* __restrict__ F,
    float* __restrict__ out0, float* __restrict__ kwout)
{
    int cc = blockIdx.x;    // 0..14
    int bg = blockIdx.y;    // 0..B/NB2_-1
    int tid = threadIdx.x;
    int c = cc * 256 + tid;
    bool act = c < C_;
    int o = act ? (c / LOUT_) : 0;
    int l = act ? (c - o * LOUT_) : 0;

    float w[KK_][KS_];
    float bk[KK_];
    #pragma unroll
    for (int k = 0; k < KK_; ++k) {
        bk[k] = bias[k * OUT_ + o];
        #pragma unroll
        for (int cq = 0; cq < KS_; ++cq) w[k][cq] = weight[(k * OUT_ + o) * KS_ + cq];
    }
    float sA = 0.f, hA = 0.f, sK = 0.f, hK = 0.f;
    if (act) {
        sA = F[c]; hA = F[C_ + c]; sK = F[2 * C_ + c]; hK = F[3 * C_ + c];
    }

    __shared__ float xs[NB2_][L_];
    __shared__ float at[NB2_][KK_];
    int b0 = bg * NB2_;
    {   // stage NB2_ rows: 256 float4, one per thread, coalesced
        const float4* xp4 = (const float4*)(x + (size_t)b0 * L_);
        ((float4*)&xs[0][0])[tid] = xp4[tid];
        if (tid < NB2_ * KK_) ((float*)at)[tid] = attn[(size_t)b0 * KK_ + tid];
    }
    __syncthreads();

    if (!act) return;

    #pragma unroll 4
    for (int r = 0; r < NB2_; ++r) {
        float kv0 = bk[0], kv1 = bk[1], kv2 = bk[2], kv3 = bk[3];
        #pragma unroll
        for (int cq = 0; cq < KS_; ++cq) {
            float xv = xs[r][l + cq];
            kv0 = fmaf(xv, w[0][cq], kv0);
            kv1 = fmaf(xv, w[1][cq], kv1);
            kv2 = fmaf(xv, w[2][cq], kv2);
            kv3 = fmaf(xv, w[3][cq], kv3);
        }
        float ov = at[r][0] * kv0;
        ov = fmaf(at[r][1], kv1, ov);
        ov = fmaf(at[r][2], kv2, ov);
        ov = fmaf(at[r][3], kv3, ov);
        int b = b0 + r;
        float g = gelu_f(ov);
        out0[(size_t)b * C_ + c] = fmaf(g, sA, hA);
        float g0 = gelu_f(kv0), g1 = gelu_f(kv1), g2v = gelu_f(kv2), g3 = gelu_f(kv3);
        size_t base = (size_t)b * KK_ * C_ + c;
        kwout[base]           = fmaf(g0,  sK, hK);
        kwout[base + C_]      = fmaf(g1,  sK, hK);
        kwout[base + 2 * C_]  = fmaf(g2v, sK, hK);
        kwout[base + 3 * C_]  = fmaf(g3,  sK, hK);
    }
}

extern "C" void kernel_launch(void* const* d_in, const int* in_sizes, int n_in,
                              void* d_out, int out_size, void* d_ws, size_t ws_size,
                              hipStream_t stream) {
    const float* x      = (const float*)d_in[0];
    const float* fc1_w  = (const float*)d_in[1];
    const float* fc2_w  = (const float*)d_in[2];
    const float* fc2_b  = (const float*)d_in[3];
    const float* weight = (const float*)d_in[4];
    const float* bias   = (const float*)d_in[5];
    const float* gamma  = (const float*)d_in[6];
    const float* beta   = (const float*)d_in[7];

    float* out  = (float*)d_out;
    float* out0 = out;                          // B*C
    float* attn = out + (size_t)B_ * C_;        // B*K
    float* kwout = attn + (size_t)B_ * KK_;     // B*K*C

    // ws layout: P (NCH_*4*C_ partials) then F (4*C_); atomic fallback uses 4*C_ + F.
    size_t need = (size_t)(NCH_ * 4 + 4) * C_ * sizeof(float);
    int use_partial = ws_size >= need;
    float* P = (float*)d_ws;
    float* F = P + (use_partial ? (size_t)NCH_ * 4 * C_ : (size_t)4 * C_);
    if (!use_partial)
        hipMemsetAsync(P, 0, 4 * C_ * sizeof(float), stream);

    attn_kernel<<<B_ / 128, 128, 0, stream>>>(x, fc1_w, fc2_w, fc2_b, attn);
    stats_kernel<<<dim3((C_ + 255) / 256, NCH_), 256, 0, stream>>>(
        x, weight, bias, attn, P, use_partial);
    finalize_kernel<<<(C_ + 255) / 256, 256, 0, stream>>>(P, gamma, beta, F, use_partial);
    write_kernel<<<dim3((C_ + 255) / 256, B_ / NB2_), 256, 0, stream>>>(
        x, weight, bias, attn, F, out0, kwout);
}

// Round 3
// 152.277 us; speedup vs baseline: 1.1815x; 1.0998x over previous
//
#include <hip/hip_runtime.h>
#include <cstddef>

#define B_     4096
#define L_     64
#define OUT_   64
#define KS_    8
#define KK_    4
#define LOUT_  57
#define C_     3648      // OUT_*LOUT_
#define HID_   33
#define TEMP_  34.0f
#define EPS_   1e-5f
#define NCH_   64        // b-chunks for stats (64 rows each)
#define SROWS_ 32        // rows staged per barrier round in stats
#define NB2_   32        // rows per block in write kernel

// gelu: x * sigmoid(1.5957691*x*(1+0.044715x^2)); max abs err ~5e-4.
// 2 transcendentals (v_exp, v_rcp) + ~5 VALU; no full-precision divide.
__device__ __forceinline__ float gelu_f(float x) {
    float u = x * fmaf(0.044715f * x, x, 1.0f) * 1.5957691216f;
    float e = __expf(-u);
    return x * __builtin_amdgcn_rcpf(1.0f + e);
}

// ---------------- kernel 1: attention weights ----------------
__global__ __launch_bounds__(128) void attn_kernel(
    const float* __restrict__ x, const float* __restrict__ fc1_w,
    const float* __restrict__ fc2_w, const float* __restrict__ fc2_b,
    float* __restrict__ attn_out)
{
    __shared__ float fc1s[HID_][L_];
    __shared__ float fc2s[KK_][HID_];
    __shared__ float fc2bs[KK_];
    int tid = threadIdx.x;
    for (int i = tid; i < HID_ * L_; i += 128) fc1s[i / L_][i % L_] = fc1_w[i];
    for (int i = tid; i < KK_ * HID_; i += 128) fc2s[i / HID_][i % HID_] = fc2_w[i];
    if (tid < KK_) fc2bs[tid] = fc2_b[tid];
    __syncthreads();

    int b = blockIdx.x * 128 + tid;
    if (b >= B_) return;

    float xr[L_];
    const float4* xp = (const float4*)(x + (size_t)b * L_);
    #pragma unroll
    for (int i = 0; i < L_ / 4; ++i) {
        float4 v = xp[i];
        xr[4*i] = v.x; xr[4*i+1] = v.y; xr[4*i+2] = v.z; xr[4*i+3] = v.w;
    }
    float logit[KK_] = {0.f, 0.f, 0.f, 0.f};
    for (int h = 0; h < HID_; ++h) {
        const float4* fr = (const float4*)&fc1s[h][0];
        float acc = 0.f;
        #pragma unroll
        for (int i = 0; i < L_ / 4; ++i) {
            float4 wv = fr[i];
            acc = fmaf(xr[4*i],   wv.x, acc);
            acc = fmaf(xr[4*i+1], wv.y, acc);
            acc = fmaf(xr[4*i+2], wv.z, acc);
            acc = fmaf(xr[4*i+3], wv.w, acc);
        }
        float a = gelu_f(acc);
        #pragma unroll
        for (int k = 0; k < KK_; ++k) logit[k] = fmaf(a, fc2s[k][h], logit[k]);
    }
    float z[KK_];
    #pragma unroll
    for (int k = 0; k < KK_; ++k) z[k] = (logit[k] + fc2bs[k]) * (1.0f / TEMP_);
    float mx = fmaxf(fmaxf(z[0], z[1]), fmaxf(z[2], z[3]));
    float e[KK_]; float s = 0.f;
    #pragma unroll
    for (int k = 0; k < KK_; ++k) { e[k] = __expf(z[k] - mx); s += e[k]; }
    float inv = __builtin_amdgcn_rcpf(s);
    #pragma unroll
    for (int k = 0; k < KK_; ++k) attn_out[(size_t)b * KK_ + k] = e[k] * inv;
}

// ---------------- kernel 2: batch statistics ----------------
// grid (15 c-tiles, NCH_ b-chunks); 64 rows/chunk staged SROWS_ at a time.
// Partial sums to P[(chunk*4 + stat)*C_ + c] (no atomics); atomic fallback.
__global__ __launch_bounds__(256) void stats_kernel(
    const float* __restrict__ x, const float* __restrict__ weight,
    const float* __restrict__ bias, const float* __restrict__ attn,
    float* __restrict__ P, int use_partial)
{
    const int RPC = B_ / NCH_;          // 64 rows per chunk
    int cb = blockIdx.x;
    int chunk = blockIdx.y;
    int tid = threadIdx.x;
    int c = cb * 256 + tid;
    bool act = c < C_;
    int o = act ? (c / LOUT_) : 0;
    int l = act ? (c - o * LOUT_) : 0;

    float w[KK_][KS_];
    float bk[KK_];
    #pragma unroll
    for (int k = 0; k < KK_; ++k) {
        bk[k] = bias[k * OUT_ + o];
        #pragma unroll
        for (int cq = 0; cq < KS_; ++cq) w[k][cq] = weight[(k * OUT_ + o) * KS_ + cq];
    }

    __shared__ float xs[SROWS_][L_];
    __shared__ float at[SROWS_][KK_];

    float s1 = 0.f, s2 = 0.f, t1 = 0.f, t2 = 0.f;

    for (int round = 0; round < RPC / SROWS_; ++round) {
        int b0 = chunk * RPC + round * SROWS_;
        __syncthreads();
        {   // stage SROWS_ rows of x: 512 float4, 2 per thread, coalesced
            const float4* xp4 = (const float4*)(x + (size_t)b0 * L_);
            float4* xd = (float4*)&xs[0][0];
            xd[tid] = xp4[tid];
            xd[tid + 256] = xp4[tid + 256];
            if (tid < SROWS_ * KK_) ((float*)at)[tid] = attn[(size_t)b0 * KK_ + tid];
        }
        __syncthreads();
        if (act) {
            #pragma unroll 4
            for (int r = 0; r < SROWS_; ++r) {
                float kv0 = bk[0], kv1 = bk[1], kv2 = bk[2], kv3 = bk[3];
                #pragma unroll
                for (int cq = 0; cq < KS_; ++cq) {
                    float xv = xs[r][l + cq];
                    kv0 = fmaf(xv, w[0][cq], kv0);
                    kv1 = fmaf(xv, w[1][cq], kv1);
                    kv2 = fmaf(xv, w[2][cq], kv2);
                    kv3 = fmaf(xv, w[3][cq], kv3);
                }
                float ov = at[r][0] * kv0;
                ov = fmaf(at[r][1], kv1, ov);
                ov = fmaf(at[r][2], kv2, ov);
                ov = fmaf(at[r][3], kv3, ov);
                float g = gelu_f(ov);
                s1 += g; s2 = fmaf(g, g, s2);
                float g0 = gelu_f(kv0), g1 = gelu_f(kv1), g2 = gelu_f(kv2), g3 = gelu_f(kv3);
                t1 += g0 + g1 + g2 + g3;
                t2 = fmaf(g0, g0, t2); t2 = fmaf(g1, g1, t2);
                t2 = fmaf(g2, g2, t2); t2 = fmaf(g3, g3, t2);
            }
        }
    }
    if (!act) return;
    if (use_partial) {
        size_t base = (size_t)chunk * 4 * C_ + c;
        P[base]          = s1;
        P[base + C_]     = s2;
        P[base + 2 * C_] = t1;
        P[base + 3 * C_] = t2;
    } else {
        atomicAdd(&P[c], s1);
        atomicAdd(&P[C_ + c], s2);
        atomicAdd(&P[2 * C_ + c], t1);
        atomicAdd(&P[3 * C_ + c], t2);
    }
}

// ---------------- kernel 3: reduce partials, fold into scale/shift ----------------
__global__ __launch_bounds__(256) void finalize_kernel(
    const float* __restrict__ P, const float* __restrict__ gamma,
    const float* __restrict__ beta, float* __restrict__ F, int use_partial)
{
    int c = blockIdx.x * 256 + threadIdx.x;
    if (c >= C_) return;
    float a0, a1, a2, a3;
    if (use_partial) {
        a0 = a1 = a2 = a3 = 0.f;
        for (int ch = 0; ch < NCH_; ++ch) {
            size_t base = (size_t)ch * 4 * C_ + c;
            a0 += P[base];
            a1 += P[base + C_];
            a2 += P[base + 2 * C_];
            a3 += P[base + 3 * C_];
        }
    } else {
        a0 = P[c]; a1 = P[C_ + c]; a2 = P[2 * C_ + c]; a3 = P[3 * C_ + c];
    }
    float m  = a0 * (1.0f / B_);
    float v  = a1 * (1.0f / B_) - m * m;
    float rs = rsqrtf(v + EPS_);
    float m2 = a2 * (1.0f / (B_ * KK_));
    float v2 = a3 * (1.0f / (B_ * KK_)) - m2 * m2;
    float rs2 = rsqrtf(v2 + EPS_);
    float ga = gamma[c], be = beta[c];
    F[c]          = rs * ga;             // scaleA
    F[C_ + c]     = be - m * rs * ga;    // shiftA
    F[2 * C_ + c] = rs2 * ga;            // scaleK
    F[3 * C_ + c] = be - m2 * rs2 * ga;  // shiftK
}

// ---------------- kernel 4: recompute + normalize + write ----------------
__global__ __launch_bounds__(256) void write_kernel(
    const float* __restrict__ x, const float* __restrict__ weight,
    const float* __restrict__ bias, const float* __restrict__ attn,
    const float* __restrict__ F,
    float* __restrict__ out0, float* __restrict__ kwout)
{
    int cc = blockIdx.x;    // 0..14
    int bg = blockIdx.y;    // 0..B/NB2_-1
    int tid = threadIdx.x;
    int c = cc * 256 + tid;
    bool act = c < C_;
    int o = act ? (c / LOUT_) : 0;
    int l = act ? (c - o * LOUT_) : 0;

    float w[KK_][KS_];
    float bk[KK_];
    #pragma unroll
    for (int k = 0; k < KK_; ++k) {
        bk[k] = bias[k * OUT_ + o];
        #pragma unroll
        for (int cq = 0; cq < KS_; ++cq) w[k][cq] = weight[(k * OUT_ + o) * KS_ + cq];
    }
    float sA = 0.f, hA = 0.f, sK = 0.f, hK = 0.f;
    if (act) {
        sA = F[c]; hA = F[C_ + c]; sK = F[2 * C_ + c]; hK = F[3 * C_ + c];
    }

    __shared__ float xs[NB2_][L_];
    __shared__ float at[NB2_][KK_];
    int b0 = bg * NB2_;
    {   // stage NB2_ rows: 512 float4, 2 per thread, coalesced
        const float4* xp4 = (const float4*)(x + (size_t)b0 * L_);
        float4* xd = (float4*)&xs[0][0];
        xd[tid] = xp4[tid];
        xd[tid + 256] = xp4[tid + 256];
        if (tid < NB2_ * KK_) ((float*)at)[tid] = attn[(size_t)b0 * KK_ + tid];
    }
    __syncthreads();

    if (!act) return;

    #pragma unroll 4
    for (int r = 0; r < NB2_; ++r) {
        float kv0 = bk[0], kv1 = bk[1], kv2 = bk[2], kv3 = bk[3];
        #pragma unroll
        for (int cq = 0; cq < KS_; ++cq) {
            float xv = xs[r][l + cq];
            kv0 = fmaf(xv, w[0][cq], kv0);
            kv1 = fmaf(xv, w[1][cq], kv1);
            kv2 = fmaf(xv, w[2][cq], kv2);
            kv3 = fmaf(xv, w[3][cq], kv3);
        }
        float ov = at[r][0] * kv0;
        ov = fmaf(at[r][1], kv1, ov);
        ov = fmaf(at[r][2], kv2, ov);
        ov = fmaf(at[r][3], kv3, ov);
        int b = b0 + r;
        float g = gelu_f(ov);
        __builtin_nontemporal_store(fmaf(g, sA, hA), &out0[(size_t)b * C_ + c]);
        float g0 = gelu_f(kv0), g1 = gelu_f(kv1), g2v = gelu_f(kv2), g3 = gelu_f(kv3);
        float* base = kwout + (size_t)b * KK_ * C_ + c;
        __builtin_nontemporal_store(fmaf(g0,  sK, hK), base);
        __builtin_nontemporal_store(fmaf(g1,  sK, hK), base + C_);
        __builtin_nontemporal_store(fmaf(g2v, sK, hK), base + 2 * C_);
        __builtin_nontemporal_store(fmaf(g3,  sK, hK), base + 3 * C_);
    }
}

extern "C" void kernel_launch(void* const* d_in, const int* in_sizes, int n_in,
                              void* d_out, int out_size, void* d_ws, size_t ws_size,
                              hipStream_t stream) {
    const float* x      = (const float*)d_in[0];
    const float* fc1_w  = (const float*)d_in[1];
    const float* fc2_w  = (const float*)d_in[2];
    const float* fc2_b  = (const float*)d_in[3];
    const float* weight = (const float*)d_in[4];
    const float* bias   = (const float*)d_in[5];
    const float* gamma  = (const float*)d_in[6];
    const float* beta   = (const float*)d_in[7];

    float* out  = (float*)d_out;
    float* out0 = out;                          // B*C
    float* attn = out + (size_t)B_ * C_;        // B*K
    float* kwout = attn + (size_t)B_ * KK_;     // B*K*C

    // ws layout: P (NCH_*4*C_ partials) then F (4*C_); atomic fallback uses 4*C_ + F.
    size_t need = (size_t)(NCH_ * 4 + 4) * C_ * sizeof(float);
    int use_partial = ws_size >= need;
    float* P = (float*)d_ws;
    float* F = P + (use_partial ? (size_t)NCH_ * 4 * C_ : (size_t)4 * C_);
    if (!use_partial)
        hipMemsetAsync(P, 0, 4 * C_ * sizeof(float), stream);

    attn_kernel<<<B_ / 128, 128, 0, stream>>>(x, fc1_w, fc2_w, fc2_b, attn);
    stats_kernel<<<dim3((C_ + 255) / 256, NCH_), 256, 0, stream>>>(
        x, weight, bias, attn, P, use_partial);
    finalize_kernel<<<(C_ + 255) / 256, 256, 0, stream>>>(P, gamma, beta, F, use_partial);
    write_kernel<<<dim3((C_ + 255) / 256, B_ / NB2_), 256, 0, stream>>>(
        x, weight, bias, attn, F, out0, kwout);
}

// Round 4
// 147.234 us; speedup vs baseline: 1.2219x; 1.0343x over previous
//
#include <hip/hip_runtime.h>
#include <cstddef>

#define B_     4096
#define L_     64
#define OUT_   64
#define KS_    8
#define KK_    4
#define LOUT_  57
#define C_     3648      // OUT_*LOUT_ = 57*64
#define HID_   33
#define TEMP_  34.0f
#define EPS_   1e-5f
#define NCH_   128       // b-chunks for stats (32 rows each)
#define SROWS_ 32        // rows staged per barrier round in stats
#define NB2_   32        // rows per block in write kernel

// gelu tanh-form: x * sigmoid(1.5957691*x*(1+0.044715x^2)); max abs err ~5e-4.
// exp2 with folded log2(e): 1 trans (v_exp) + 1 trans (v_rcp) + 4 VALU.
__device__ __forceinline__ float gelu_f(float x) {
    float e = exp2f(-2.3022083f * x * fmaf(0.044715f * x, x, 1.0f));
    return x * __builtin_amdgcn_rcpf(1.0f + e);
}

// ---------------- kernel 1: attention weights ----------------
__global__ __launch_bounds__(128) void attn_kernel(
    const float* __restrict__ x, const float* __restrict__ fc1_w,
    const float* __restrict__ fc2_w, const float* __restrict__ fc2_b,
    float* __restrict__ attn_out)
{
    __shared__ float fc1s[HID_][L_];
    __shared__ float fc2s[KK_][HID_];
    __shared__ float fc2bs[KK_];
    int tid = threadIdx.x;
    for (int i = tid; i < HID_ * L_; i += 128) fc1s[i / L_][i % L_] = fc1_w[i];
    for (int i = tid; i < KK_ * HID_; i += 128) fc2s[i / HID_][i % HID_] = fc2_w[i];
    if (tid < KK_) fc2bs[tid] = fc2_b[tid];
    __syncthreads();

    int b = blockIdx.x * 128 + tid;
    if (b >= B_) return;

    float xr[L_];
    const float4* xp = (const float4*)(x + (size_t)b * L_);
    #pragma unroll
    for (int i = 0; i < L_ / 4; ++i) {
        float4 v = xp[i];
        xr[4*i] = v.x; xr[4*i+1] = v.y; xr[4*i+2] = v.z; xr[4*i+3] = v.w;
    }
    float logit[KK_] = {0.f, 0.f, 0.f, 0.f};
    for (int h = 0; h < HID_; ++h) {
        const float4* fr = (const float4*)&fc1s[h][0];
        float acc = 0.f;
        #pragma unroll
        for (int i = 0; i < L_ / 4; ++i) {
            float4 wv = fr[i];
            acc = fmaf(xr[4*i],   wv.x, acc);
            acc = fmaf(xr[4*i+1], wv.y, acc);
            acc = fmaf(xr[4*i+2], wv.z, acc);
            acc = fmaf(xr[4*i+3], wv.w, acc);
        }
        float a = gelu_f(acc);
        #pragma unroll
        for (int k = 0; k < KK_; ++k) logit[k] = fmaf(a, fc2s[k][h], logit[k]);
    }
    float z[KK_];
    #pragma unroll
    for (int k = 0; k < KK_; ++k) z[k] = (logit[k] + fc2bs[k]) * (1.0f / TEMP_);
    float mx = fmaxf(fmaxf(z[0], z[1]), fmaxf(z[2], z[3]));
    float e[KK_]; float s = 0.f;
    #pragma unroll
    for (int k = 0; k < KK_; ++k) { e[k] = __expf(z[k] - mx); s += e[k]; }
    float inv = __builtin_amdgcn_rcpf(s);
    #pragma unroll
    for (int k = 0; k < KK_; ++k) attn_out[(size_t)b * KK_ + k] = e[k] * inv;
}

// ---------------- kernel 2: batch statistics ----------------
// grid (15 c-tiles, NCH_ b-chunks of 32 rows); partial sums to
// P[(chunk*4 + stream)*C_ + c] (no atomics); atomic fallback if ws too small.
__global__ __launch_bounds__(256) void stats_kernel(
    const float* __restrict__ x, const float* __restrict__ weight,
    const float* __restrict__ bias, const float* __restrict__ attn,
    float* __restrict__ P, int use_partial)
{
    const int RPC = B_ / NCH_;          // 32 rows per chunk
    int cb = blockIdx.x;
    int chunk = blockIdx.y;
    int tid = threadIdx.x;
    int c = cb * 256 + tid;
    bool act = c < C_;
    int o = act ? (c / LOUT_) : 0;
    int l = act ? (c - o * LOUT_) : 0;

    float w[KK_][KS_];
    float bk[KK_];
    #pragma unroll
    for (int k = 0; k < KK_; ++k) {
        bk[k] = bias[k * OUT_ + o];
        #pragma unroll
        for (int cq = 0; cq < KS_; ++cq) w[k][cq] = weight[(k * OUT_ + o) * KS_ + cq];
    }

    __shared__ float xs[SROWS_][L_];
    __shared__ float at[SROWS_][KK_];

    float s1 = 0.f, s2 = 0.f, t1 = 0.f, t2 = 0.f;

    for (int round = 0; round < RPC / SROWS_; ++round) {
        int b0 = chunk * RPC + round * SROWS_;
        __syncthreads();
        {   // stage SROWS_ rows of x: 512 float4, 2 per thread, coalesced
            const float4* xp4 = (const float4*)(x + (size_t)b0 * L_);
            float4* xd = (float4*)&xs[0][0];
            xd[tid] = xp4[tid];
            xd[tid + 256] = xp4[tid + 256];
            if (tid < SROWS_ * KK_) ((float*)at)[tid] = attn[(size_t)b0 * KK_ + tid];
        }
        __syncthreads();
        if (act) {
            #pragma unroll 4
            for (int r = 0; r < SROWS_; ++r) {
                float kv0 = bk[0], kv1 = bk[1], kv2 = bk[2], kv3 = bk[3];
                #pragma unroll
                for (int cq = 0; cq < KS_; ++cq) {
                    float xv = xs[r][l + cq];
                    kv0 = fmaf(xv, w[0][cq], kv0);
                    kv1 = fmaf(xv, w[1][cq], kv1);
                    kv2 = fmaf(xv, w[2][cq], kv2);
                    kv3 = fmaf(xv, w[3][cq], kv3);
                }
                float ov = at[r][0] * kv0;
                ov = fmaf(at[r][1], kv1, ov);
                ov = fmaf(at[r][2], kv2, ov);
                ov = fmaf(at[r][3], kv3, ov);
                float g = gelu_f(ov);
                s1 += g; s2 = fmaf(g, g, s2);
                float g0 = gelu_f(kv0), g1 = gelu_f(kv1), g2 = gelu_f(kv2), g3 = gelu_f(kv3);
                t1 += g0 + g1 + g2 + g3;
                t2 = fmaf(g0, g0, t2); t2 = fmaf(g1, g1, t2);
                t2 = fmaf(g2, g2, t2); t2 = fmaf(g3, g3, t2);
            }
        }
    }
    if (!act) return;
    if (use_partial) {
        size_t base = (size_t)chunk * 4 * C_ + c;
        P[base]          = s1;
        P[base + C_]     = s2;
        P[base + 2 * C_] = t1;
        P[base + 3 * C_] = t2;
    } else {
        atomicAdd(&P[c], s1);
        atomicAdd(&P[C_ + c], s2);
        atomicAdd(&P[2 * C_ + c], t1);
        atomicAdd(&P[3 * C_ + c], t2);
    }
}

// ---------------- kernel 3: reduce partials, fold into scale/shift ----------------
// grid 57 blocks; block handles 64 c. thread = (stream s = t>>6, c_local = t&63);
// each thread sums its stream over all NCH_ chunks (coalesced), LDS exchange,
// then 64 threads compute the 4 F outputs per c.
__global__ __launch_bounds__(256) void finalize_kernel(
    const float* __restrict__ P, const float* __restrict__ gamma,
    const float* __restrict__ beta, float* __restrict__ F, int use_partial)
{
    __shared__ float red[4][64];
    int t = threadIdx.x;
    int cl = t & 63;
    int s = t >> 6;
    int c = blockIdx.x * 64 + cl;    // C_ = 57*64, always in range
    float a = 0.f;
    if (use_partial) {
        for (int ch = 0; ch < NCH_; ++ch)
            a += P[((size_t)ch * 4 + s) * C_ + c];
    } else {
        a = P[(size_t)s * C_ + c];
    }
    red[s][cl] = a;
    __syncthreads();
    if (t < 64) {
        float a0 = red[0][cl], a1 = red[1][cl], a2 = red[2][cl], a3 = red[3][cl];
        float m  = a0 * (1.0f / B_);
        float v  = a1 * (1.0f / B_) - m * m;
        float rs = rsqrtf(v + EPS_);
        float m2 = a2 * (1.0f / (B_ * KK_));
        float v2 = a3 * (1.0f / (B_ * KK_)) - m2 * m2;
        float rs2 = rsqrtf(v2 + EPS_);
        float ga = gamma[c], be = beta[c];
        F[c]          = rs * ga;             // scaleA
        F[C_ + c]     = be - m * rs * ga;    // shiftA
        F[2 * C_ + c] = rs2 * ga;            // scaleK
        F[3 * C_ + c] = be - m2 * rs2 * ga;  // shiftK
    }
}

// ---------------- kernel 4: recompute + normalize + write ----------------
__global__ __launch_bounds__(256) void write_kernel(
    const float* __restrict__ x, const float* __restrict__ weight,
    const float* __restrict__ bias, const float* __restrict__ attn,
    const float* __restrict__ F,
    float* __restrict__ out0, float* __restrict__ kwout)
{
    int cc = blockIdx.x;    // 0..14
    int bg = blockIdx.y;    // 0..B/NB2_-1
    int tid = threadIdx.x;
    int c = cc * 256 + tid;
    bool act = c < C_;
    int o = act ? (c / LOUT_) : 0;
    int l = act ? (c - o * LOUT_) : 0;

    float w[KK_][KS_];
    float bk[KK_];
    #pragma unroll
    for (int k = 0; k < KK_; ++k) {
        bk[k] = bias[k * OUT_ + o];
        #pragma unroll
        for (int cq = 0; cq < KS_; ++cq) w[k][cq] = weight[(k * OUT_ + o) * KS_ + cq];
    }
    float sA = 0.f, hA = 0.f, sK = 0.f, hK = 0.f;
    if (act) {
        sA = F[c]; hA = F[C_ + c]; sK = F[2 * C_ + c]; hK = F[3 * C_ + c];
    }

    __shared__ float xs[NB2_][L_];
    __shared__ float at[NB2_][KK_];
    int b0 = bg * NB2_;
    {   // stage NB2_ rows: 512 float4, 2 per thread, coalesced
        const float4* xp4 = (const float4*)(x + (size_t)b0 * L_);
        float4* xd = (float4*)&xs[0][0];
        xd[tid] = xp4[tid];
        xd[tid + 256] = xp4[tid + 256];
        if (tid < NB2_ * KK_) ((float*)at)[tid] = attn[(size_t)b0 * KK_ + tid];
    }
    __syncthreads();

    if (!act) return;

    #pragma unroll 4
    for (int r = 0; r < NB2_; ++r) {
        float kv0 = bk[0], kv1 = bk[1], kv2 = bk[2], kv3 = bk[3];
        #pragma unroll
        for (int cq = 0; cq < KS_; ++cq) {
            float xv = xs[r][l + cq];
            kv0 = fmaf(xv, w[0][cq], kv0);
            kv1 = fmaf(xv, w[1][cq], kv1);
            kv2 = fmaf(xv, w[2][cq], kv2);
            kv3 = fmaf(xv, w[3][cq], kv3);
        }
        float ov = at[r][0] * kv0;
        ov = fmaf(at[r][1], kv1, ov);
        ov = fmaf(at[r][2], kv2, ov);
        ov = fmaf(at[r][3], kv3, ov);
        int b = b0 + r;
        float g = gelu_f(ov);
        out0[(size_t)b * C_ + c] = fmaf(g, sA, hA);
        float g0 = gelu_f(kv0), g1 = gelu_f(kv1), g2v = gelu_f(kv2), g3 = gelu_f(kv3);
        float* base = kwout + (size_t)b * KK_ * C_ + c;
        base[0]      = fmaf(g0,  sK, hK);
        base[C_]     = fmaf(g1,  sK, hK);
        base[2 * C_] = fmaf(g2v, sK, hK);
        base[3 * C_] = fmaf(g3,  sK, hK);
    }
}

extern "C" void kernel_launch(void* const* d_in, const int* in_sizes, int n_in,
                              void* d_out, int out_size, void* d_ws, size_t ws_size,
                              hipStream_t stream) {
    const float* x      = (const float*)d_in[0];
    const float* fc1_w  = (const float*)d_in[1];
    const float* fc2_w  = (const float*)d_in[2];
    const float* fc2_b  = (const float*)d_in[3];
    const float* weight = (const float*)d_in[4];
    const float* bias   = (const float*)d_in[5];
    const float* gamma  = (const float*)d_in[6];
    const float* beta   = (const float*)d_in[7];

    float* out  = (float*)d_out;
    float* out0 = out;                          // B*C
    float* attn = out + (size_t)B_ * C_;        // B*K
    float* kwout = attn + (size_t)B_ * KK_;     // B*K*C

    // ws layout: P (NCH_*4*C_ partials) then F (4*C_); atomic fallback uses 4*C_ + F.
    size_t need = (size_t)(NCH_ * 4 + 4) * C_ * sizeof(float);
    int use_partial = ws_size >= need;
    float* P = (float*)d_ws;
    float* F = P + (use_partial ? (size_t)NCH_ * 4 * C_ : (size_t)4 * C_);
    if (!use_partial)
        hipMemsetAsync(P, 0, 4 * C_ * sizeof(float), stream);

    attn_kernel<<<B_ / 128, 128, 0, stream>>>(x, fc1_w, fc2_w, fc2_b, attn);
    stats_kernel<<<dim3((C_ + 255) / 256, NCH_), 256, 0, stream>>>(
        x, weight, bias, attn, P, use_partial);
    finalize_kernel<<<C_ / 64, 256, 0, stream>>>(P, gamma, beta, F, use_partial);
    write_kernel<<<dim3((C_ + 255) / 256, B_ / NB2_), 256, 0, stream>>>(
        x, weight, bias, attn, F, out0, kwout);
}

// Round 5
// 145.652 us; speedup vs baseline: 1.2352x; 1.0109x over previous
//
#include <hip/hip_runtime.h>
#include <cstddef>

#define B_     4096
#define L_     64
#define OUT_   64
#define KS_    8
#define KK_    4
#define LOUT_  57
#define C_     3648      // OUT_*LOUT_ = 57*64
#define HID_   33
#define TEMP_  34.0f
#define EPS_   1e-5f
#define NCH_   128       // b-chunks for stats (32 rows each)
#define SROWS_ 32        // rows per stats block (single staging round)
#define NB2_   32        // rows per block in write kernel

// gelu tanh-form: x * sigmoid(1.5957691*x*(1+0.044715x^2)); max abs err ~5e-4.
__device__ __forceinline__ float gelu_f(float x) {
    float e = exp2f(-2.3022083f * x * fmaf(0.044715f * x, x, 1.0f));
    return x * __builtin_amdgcn_rcpf(1.0f + e);
}

// Stage ROWS rows of x into 4 byte-shifted LDS copies:
//   xs4[s][r][t] = float4{ x[r][4t+s], x[r][4t+s+1], x[r][4t+s+2], x[r][4t+s+3] }
// so a window x[r][l..l+7] = slots (l>>2) and (l>>2)+1 of copy (l&3): 2 ds_read_b128.
// (l<=56 guarantees s>=1 never needs slot 15, so the t=15 clamp garbage is never read.)
template<int ROWS>
__device__ __forceinline__ void stage_shifted(
    const float* __restrict__ x, int b0, int tid,
    float4 (*xs4)[ROWS][17])
{
    for (int idx = tid; idx < ROWS * 16; idx += 256) {
        int r = idx >> 4, t = idx & 15;
        const float4* xrow = (const float4*)(x + (size_t)(b0 + r) * L_);
        float4 a  = xrow[t];
        float4 bq = xrow[t < 15 ? t + 1 : 15];
        xs4[0][r][t] = a;
        xs4[1][r][t] = make_float4(a.y, a.z, a.w, bq.x);
        xs4[2][r][t] = make_float4(a.z, a.w, bq.x, bq.y);
        xs4[3][r][t] = make_float4(a.w, bq.x, bq.y, bq.z);
    }
}

// ---------------- kernel 1: attention weights ----------------
__global__ __launch_bounds__(128) void attn_kernel(
    const float* __restrict__ x, const float* __restrict__ fc1_w,
    const float* __restrict__ fc2_w, const float* __restrict__ fc2_b,
    float* __restrict__ attn_out)
{
    __shared__ float fc1s[HID_][L_];
    __shared__ float fc2s[KK_][HID_];
    __shared__ float fc2bs[KK_];
    int tid = threadIdx.x;
    for (int i = tid; i < HID_ * L_; i += 128) fc1s[i / L_][i % L_] = fc1_w[i];
    for (int i = tid; i < KK_ * HID_; i += 128) fc2s[i / HID_][i % HID_] = fc2_w[i];
    if (tid < KK_) fc2bs[tid] = fc2_b[tid];
    __syncthreads();

    int b = blockIdx.x * 128 + tid;
    if (b >= B_) return;

    float xr[L_];
    const float4* xp = (const float4*)(x + (size_t)b * L_);
    #pragma unroll
    for (int i = 0; i < L_ / 4; ++i) {
        float4 v = xp[i];
        xr[4*i] = v.x; xr[4*i+1] = v.y; xr[4*i+2] = v.z; xr[4*i+3] = v.w;
    }
    float logit[KK_] = {0.f, 0.f, 0.f, 0.f};
    for (int h = 0; h < HID_; ++h) {
        const float4* fr = (const float4*)&fc1s[h][0];
        float acc = 0.f;
        #pragma unroll
        for (int i = 0; i < L_ / 4; ++i) {
            float4 wv = fr[i];
            acc = fmaf(xr[4*i],   wv.x, acc);
            acc = fmaf(xr[4*i+1], wv.y, acc);
            acc = fmaf(xr[4*i+2], wv.z, acc);
            acc = fmaf(xr[4*i+3], wv.w, acc);
        }
        float a = gelu_f(acc);
        #pragma unroll
        for (int k = 0; k < KK_; ++k) logit[k] = fmaf(a, fc2s[k][h], logit[k]);
    }
    float z[KK_];
    #pragma unroll
    for (int k = 0; k < KK_; ++k) z[k] = (logit[k] + fc2bs[k]) * (1.0f / TEMP_);
    float mx = fmaxf(fmaxf(z[0], z[1]), fmaxf(z[2], z[3]));
    float e[KK_]; float s = 0.f;
    #pragma unroll
    for (int k = 0; k < KK_; ++k) { e[k] = __expf(z[k] - mx); s += e[k]; }
    float inv = __builtin_amdgcn_rcpf(s);
    #pragma unroll
    for (int k = 0; k < KK_; ++k) attn_out[(size_t)b * KK_ + k] = e[k] * inv;
}

// ---------------- kernel 2: batch statistics ----------------
__global__ __launch_bounds__(256) void stats_kernel(
    const float* __restrict__ x, const float* __restrict__ weight,
    const float* __restrict__ bias, const float* __restrict__ attn,
    float* __restrict__ P, int use_partial)
{
    int cb = blockIdx.x;
    int chunk = blockIdx.y;
    int tid = threadIdx.x;
    int c = cb * 256 + tid;
    bool act = c < C_;
    int o = act ? (c / LOUT_) : 0;
    int l = act ? (c - o * LOUT_) : 0;
    int q = l >> 2, s = l & 3;

    float w[KK_][KS_];
    float bk[KK_];
    #pragma unroll
    for (int k = 0; k < KK_; ++k) {
        bk[k] = bias[k * OUT_ + o];
        #pragma unroll
        for (int cq = 0; cq < KS_; ++cq) w[k][cq] = weight[(k * OUT_ + o) * KS_ + cq];
    }

    __shared__ float4 xs4[4][SROWS_][17];
    __shared__ float at[SROWS_][KK_];

    int b0 = chunk * SROWS_;
    stage_shifted<SROWS_>(x, b0, tid, xs4);
    if (tid < SROWS_ * KK_) ((float*)at)[tid] = attn[(size_t)b0 * KK_ + tid];
    __syncthreads();

    float s1 = 0.f, s2 = 0.f, t1 = 0.f, t2 = 0.f;
    if (act) {
        const float4* base = &xs4[s][0][q];
        #pragma unroll 4
        for (int r = 0; r < SROWS_; ++r) {
            float4 A  = base[(size_t)r * 17];
            float4 Bv = base[(size_t)r * 17 + 1];
            float xw[8] = {A.x, A.y, A.z, A.w, Bv.x, Bv.y, Bv.z, Bv.w};
            float kv0 = bk[0], kv1 = bk[1], kv2 = bk[2], kv3 = bk[3];
            #pragma unroll
            for (int cq = 0; cq < KS_; ++cq) {
                float xv = xw[cq];
                kv0 = fmaf(xv, w[0][cq], kv0);
                kv1 = fmaf(xv, w[1][cq], kv1);
                kv2 = fmaf(xv, w[2][cq], kv2);
                kv3 = fmaf(xv, w[3][cq], kv3);
            }
            float ov = at[r][0] * kv0;
            ov = fmaf(at[r][1], kv1, ov);
            ov = fmaf(at[r][2], kv2, ov);
            ov = fmaf(at[r][3], kv3, ov);
            float g = gelu_f(ov);
            s1 += g; s2 = fmaf(g, g, s2);
            float g0 = gelu_f(kv0), g1 = gelu_f(kv1), g2 = gelu_f(kv2), g3 = gelu_f(kv3);
            t1 += g0 + g1 + g2 + g3;
            t2 = fmaf(g0, g0, t2); t2 = fmaf(g1, g1, t2);
            t2 = fmaf(g2, g2, t2); t2 = fmaf(g3, g3, t2);
        }
    }
    if (!act) return;
    if (use_partial) {
        size_t base = (size_t)chunk * 4 * C_ + c;
        P[base]          = s1;
        P[base + C_]     = s2;
        P[base + 2 * C_] = t1;
        P[base + 3 * C_] = t2;
    } else {
        atomicAdd(&P[c], s1);
        atomicAdd(&P[C_ + c], s2);
        atomicAdd(&P[2 * C_ + c], t1);
        atomicAdd(&P[3 * C_ + c], t2);
    }
}

// ---------------- kernel 3: reduce partials, fold into scale/shift ----------------
__global__ __launch_bounds__(256) void finalize_kernel(
    const float* __restrict__ P, const float* __restrict__ gamma,
    const float* __restrict__ beta, float* __restrict__ F, int use_partial)
{
    __shared__ float red[4][64];
    int t = threadIdx.x;
    int cl = t & 63;
    int s = t >> 6;
    int c = blockIdx.x * 64 + cl;    // C_ = 57*64, always in range
    float a = 0.f;
    if (use_partial) {
        for (int ch = 0; ch < NCH_; ++ch)
            a += P[((size_t)ch * 4 + s) * C_ + c];
    } else {
        a = P[(size_t)s * C_ + c];
    }
    red[s][cl] = a;
    __syncthreads();
    if (t < 64) {
        float a0 = red[0][cl], a1 = red[1][cl], a2 = red[2][cl], a3 = red[3][cl];
        float m  = a0 * (1.0f / B_);
        float v  = a1 * (1.0f / B_) - m * m;
        float rs = rsqrtf(v + EPS_);
        float m2 = a2 * (1.0f / (B_ * KK_));
        float v2 = a3 * (1.0f / (B_ * KK_)) - m2 * m2;
        float rs2 = rsqrtf(v2 + EPS_);
        float ga = gamma[c], be = beta[c];
        F[c]          = rs * ga;             // scaleA
        F[C_ + c]     = be - m * rs * ga;    // shiftA
        F[2 * C_ + c] = rs2 * ga;            // scaleK
        F[3 * C_ + c] = be - m2 * rs2 * ga;  // shiftK
    }
}

// ---------------- kernel 4: recompute + normalize + write ----------------
__global__ __launch_bounds__(256) void write_kernel(
    const float* __restrict__ x, const float* __restrict__ weight,
    const float* __restrict__ bias, const float* __restrict__ attn,
    const float* __restrict__ F,
    float* __restrict__ out0, float* __restrict__ kwout)
{
    int cc = blockIdx.x;    // 0..14
    int bg = blockIdx.y;    // 0..B/NB2_-1
    int tid = threadIdx.x;
    int c = cc * 256 + tid;
    bool act = c < C_;
    int o = act ? (c / LOUT_) : 0;
    int l = act ? (c - o * LOUT_) : 0;
    int q = l >> 2, s = l & 3;

    float w[KK_][KS_];
    float bk[KK_];
    #pragma unroll
    for (int k = 0; k < KK_; ++k) {
        bk[k] = bias[k * OUT_ + o];
        #pragma unroll
        for (int cq = 0; cq < KS_; ++cq) w[k][cq] = weight[(k * OUT_ + o) * KS_ + cq];
    }
    float sA = 0.f, hA = 0.f, sK = 0.f, hK = 0.f;
    if (act) {
        sA = F[c]; hA = F[C_ + c]; sK = F[2 * C_ + c]; hK = F[3 * C_ + c];
    }

    __shared__ float4 xs4[4][NB2_][17];
    __shared__ float at[NB2_][KK_];
    int b0 = bg * NB2_;
    stage_shifted<NB2_>(x, b0, tid, xs4);
    if (tid < NB2_ * KK_) ((float*)at)[tid] = attn[(size_t)b0 * KK_ + tid];
    __syncthreads();

    if (!act) return;

    const float4* xbase = &xs4[s][0][q];
    #pragma unroll 4
    for (int r = 0; r < NB2_; ++r) {
        float4 A  = xbase[(size_t)r * 17];
        float4 Bv = xbase[(size_t)r * 17 + 1];
        float xw[8] = {A.x, A.y, A.z, A.w, Bv.x, Bv.y, Bv.z, Bv.w};
        float kv0 = bk[0], kv1 = bk[1], kv2 = bk[2], kv3 = bk[3];
        #pragma unroll
        for (int cq = 0; cq < KS_; ++cq) {
            float xv = xw[cq];
            kv0 = fmaf(xv, w[0][cq], kv0);
            kv1 = fmaf(xv, w[1][cq], kv1);
            kv2 = fmaf(xv, w[2][cq], kv2);
            kv3 = fmaf(xv, w[3][cq], kv3);
        }
        float ov = at[r][0] * kv0;
        ov = fmaf(at[r][1], kv1, ov);
        ov = fmaf(at[r][2], kv2, ov);
        ov = fmaf(at[r][3], kv3, ov);
        int b = b0 + r;
        float g = gelu_f(ov);
        out0[(size_t)b * C_ + c] = fmaf(g, sA, hA);
        float g0 = gelu_f(kv0), g1 = gelu_f(kv1), g2v = gelu_f(kv2), g3 = gelu_f(kv3);
        float* base = kwout + (size_t)b * KK_ * C_ + c;
        base[0]      = fmaf(g0,  sK, hK);
        base[C_]     = fmaf(g1,  sK, hK);
        base[2 * C_] = fmaf(g2v, sK, hK);
        base[3 * C_] = fmaf(g3,  sK, hK);
    }
}

extern "C" void kernel_launch(void* const* d_in, const int* in_sizes, int n_in,
                              void* d_out, int out_size, void* d_ws, size_t ws_size,
                              hipStream_t stream) {
    const float* x      = (const float*)d_in[0];
    const float* fc1_w  = (const float*)d_in[1];
    const float* fc2_w  = (const float*)d_in[2];
    const float* fc2_b  = (const float*)d_in[3];
    const float* weight = (const float*)d_in[4];
    const float* bias   = (const float*)d_in[5];
    const float* gamma  = (const float*)d_in[6];
    const float* beta   = (const float*)d_in[7];

    float* out  = (float*)d_out;
    float* out0 = out;                          // B*C
    float* attn = out + (size_t)B_ * C_;        // B*K
    float* kwout = attn + (size_t)B_ * KK_;     // B*K*C

    // ws layout: P (NCH_*4*C_ partials) then F (4*C_); atomic fallback uses 4*C_ + F.
    size_t need = (size_t)(NCH_ * 4 + 4) * C_ * sizeof(float);
    int use_partial = ws_size >= need;
    float* P = (float*)d_ws;
    float* F = P + (use_partial ? (size_t)NCH_ * 4 * C_ : (size_t)4 * C_);
    if (!use_partial)
        hipMemsetAsync(P, 0, 4 * C_ * sizeof(float), stream);

    attn_kernel<<<B_ / 128, 128, 0, stream>>>(x, fc1_w, fc2_w, fc2_b, attn);
    stats_kernel<<<dim3((C_ + 255) / 256, NCH_), 256, 0, stream>>>(
        x, weight, bias, attn, P, use_partial);
    finalize_kernel<<<C_ / 64, 256, 0, stream>>>(P, gamma, beta, F, use_partial);
    write_kernel<<<dim3((C_ + 255) / 256, B_ / NB2_), 256, 0, stream>>>(
        x, weight, bias, attn, F, out0, kwout);
}